// Round 13
// baseline (229.314 us; speedup 1.0000x reference)
//
#include <hip/hip_runtime.h>
#include <hip/hip_bf16.h>

#define N_NODES 100000
#define N_EDGES 1600000
#define F_IN    512
#define HID     64
#define NCLS    16

#define SCAN_NB 98      // ceil(100000 / 1024) = # of 1024-node buckets
#define BM      128     // gemm1 row tile
#define PA_EPB  4096    // partition edges per block
#define PA_NB   ((N_EDGES + PA_EPB - 1) / PA_EPB)   // 391

typedef __attribute__((ext_vector_type(8))) short short8;
typedef __attribute__((ext_vector_type(4))) float f32x4;
typedef unsigned int u32;
typedef unsigned short u16;

// ---------------------------------------------------------------------------
// async global->LDS 16B (wave-uniform LDS base + lane*16 dest semantics)
// ---------------------------------------------------------------------------
__device__ inline void gload_lds16(const float* g, float* l) {
    __builtin_amdgcn_global_load_lds(
        (const __attribute__((address_space(1))) u32*)g,
        (__attribute__((address_space(3))) u32*)l, 16, 0, 0);
}

// ---------------------------------------------------------------------------
// CSR build 1: per-block bucket histogram -> blockhist[bucket][block]
// ---------------------------------------------------------------------------
__global__ __launch_bounds__(256) void bhist(const int* __restrict__ edst,
                                             int* __restrict__ bh) {
    __shared__ int hist[SCAN_NB];
    int tid = threadIdx.x;
    int e00 = blockIdx.x * PA_EPB;
    for (int i = tid; i < SCAN_NB; i += 256) hist[i] = 0;
    __syncthreads();
    #pragma unroll
    for (int j = 0; j < PA_EPB / 256; j++) {
        int e = e00 + j * 256 + tid;
        if (e < N_EDGES) atomicAdd(&hist[edst[e] >> 10], 1);
    }
    __syncthreads();
    for (int i = tid; i < SCAN_NB; i += 256)
        bh[i * PA_NB + blockIdx.x] = hist[i];
}

// ---------------------------------------------------------------------------
// CSR build 2: per bucket, exclusive scan over the 391 block counts
// ---------------------------------------------------------------------------
__global__ __launch_bounds__(512) void colscan(int* __restrict__ bh,
                                               int* __restrict__ bsums) {
    __shared__ int sc[512];
    int t = threadIdx.x;
    int b = blockIdx.x;
    int v = (t < PA_NB) ? bh[b * PA_NB + t] : 0;
    sc[t] = v;
    __syncthreads();
    #pragma unroll
    for (int d = 1; d < 512; d <<= 1) {
        int u = (t >= d) ? sc[t - d] : 0;
        __syncthreads();
        sc[t] += u;
        __syncthreads();
    }
    if (t < PA_NB) bh[b * PA_NB + t] = sc[t] - v;   // exclusive
    if (t == 511) bsums[b] = sc[511];
}

// ---------------------------------------------------------------------------
// CSR build 3: exclusive scan of bucket sums -> bbase; off[N]=E.
// ---------------------------------------------------------------------------
__global__ __launch_bounds__(128) void scan_top(const int* __restrict__ bsums,
                                                int* __restrict__ bbase,
                                                int* __restrict__ off) {
    __shared__ int sc[128];
    int t = threadIdx.x;
    int v0 = (t < SCAN_NB) ? bsums[t] : 0;
    sc[t] = v0;
    __syncthreads();
    #pragma unroll
    for (int d = 1; d < 128; d <<= 1) {
        int v = (t >= d) ? sc[t - d] : 0;
        __syncthreads();
        sc[t] += v;
        __syncthreads();
    }
    bbase[t] = sc[t] - v0;
    if (t == 0) off[N_NODES] = N_EDGES;
}

// ---------------------------------------------------------------------------
// CSR build 4: bucket edges by dst>>10 into mid[]; deterministic
// reservations (bbase + scanned blockhist); LDS cursors only.
// mid.x packs src (17b) | dst_low10 << 17 ; mid.y = val bits.
// ---------------------------------------------------------------------------
__global__ __launch_bounds__(256) void partA2(const int* __restrict__ esrc,
                                              const int* __restrict__ edst,
                                              const float* __restrict__ eval_,
                                              const int* __restrict__ bh,
                                              const int* __restrict__ bbase,
                                              int2* __restrict__ mid) {
    __shared__ int curs[SCAN_NB];
    int tid = threadIdx.x;
    int blk = blockIdx.x;
    int e00 = blk * PA_EPB;
    for (int i = tid; i < SCAN_NB; i += 256)
        curs[i] = bbase[i] + bh[i * PA_NB + blk];
    __syncthreads();
    #pragma unroll
    for (int j = 0; j < PA_EPB / 256; j++) {
        int e = e00 + j * 256 + tid;
        if (e < N_EDGES) {
            int d = edst[e];
            int b = d >> 10;
            int pos = atomicAdd(&curs[b], 1);
            mid[pos] = make_int2(esrc[e] | ((d & 1023) << 17),
                                 __float_as_int(eval_[e]));
        }
    }
}

// ---------------------------------------------------------------------------
// CSR build 5: within-bucket final scatter; node degrees + LDS scan ->
// off[] and cursors locally; zero global atomics.
// ---------------------------------------------------------------------------
__global__ __launch_bounds__(512) void partB2(const int* __restrict__ bbase,
                                              const int* __restrict__ bsums,
                                              const int2* __restrict__ mid,
                                              int2* __restrict__ epk,
                                              int* __restrict__ off) {
    __shared__ int nh[1024];
    __shared__ int sc[512];
    int t = threadIdx.x;
    int b = blockIdx.x;
    int start = bbase[b];
    int cntb  = bsums[b];

    nh[t] = 0; nh[t + 512] = 0;
    __syncthreads();

    for (int i = t; i < cntb; i += 512) {
        u32 ux = (u32)mid[start + i].x;
        atomicAdd(&nh[ux >> 17], 1);
    }
    __syncthreads();

    int c0 = nh[2 * t], c1 = nh[2 * t + 1];
    int s = c0 + c1;
    sc[t] = s;
    __syncthreads();
    #pragma unroll
    for (int d = 1; d < 512; d <<= 1) {
        int u = (t >= d) ? sc[t - d] : 0;
        __syncthreads();
        sc[t] += u;
        __syncthreads();
    }
    int ex = start + sc[t] - s;

    nh[2 * t]     = ex;
    nh[2 * t + 1] = ex + c0;
    int node = (b << 10) + 2 * t;
    if (node < N_NODES)     off[node]     = ex;
    if (node + 1 < N_NODES) off[node + 1] = ex + c0;
    __syncthreads();

    for (int i = t; i < cntb; i += 512) {
        int2 m = mid[start + i];
        u32 ux = (u32)m.x;
        int pos = atomicAdd(&nh[ux >> 17], 1);
        epk[pos] = make_int2((int)(ux & 0x1FFFF), m.y);
    }
}

// ---------------------------------------------------------------------------
// split fp32 -> bf16 hi + bf16 lo (truncation; residual ~2^-16 relative)
// ---------------------------------------------------------------------------
__device__ inline void split_bf16(float a, unsigned short& hi, unsigned short& lo) {
    unsigned u = __float_as_uint(a);
    hi = (unsigned short)(u >> 16);
    float hif = __uint_as_float(((unsigned)hi) << 16);
    float lof = a - hif;
    lo = (unsigned short)(__float_as_uint(lof) >> 16);
}

// split 8 fp32 (two f32x4) into hi/lo short8 fragments
__device__ inline void split8(f32x4 a, f32x4 b, short8& hi, short8& lo) {
    #pragma unroll
    for (int i = 0; i < 4; i++) {
        u16 h, l;
        split_bf16(a[i], h, l);
        hi[i] = (short)h; lo[i] = (short)l;
    }
    #pragma unroll
    for (int i = 0; i < 4; i++) {
        u16 h, l;
        split_bf16(b[i], h, l);
        hi[4 + i] = (short)h; lo[4 + i] = (short)l;
    }
}

// ---------------------------------------------------------------------------
// prep: W1 [512][64] fp32 -> Wg fragment-native bf16 hi/lo layout
// Wg[nt(4)][kc(16)][h(2)][lane(64)][j(8)] ushort:
//   lane l loads 16B holding n = nt*16 + (l&15), k = kc*32 + (l>>4)*8 + j
// ---------------------------------------------------------------------------
__global__ __launch_bounds__(256) void prep_w1(const float* __restrict__ W1,
                                               unsigned short* __restrict__ Wg) {
    int idx = blockIdx.x * 256 + threadIdx.x;   // 0 .. 32767
    if (idx >= F_IN * HID) return;
    int k = idx >> 6, n = idx & 63;
    unsigned short hi, lo;
    split_bf16(W1[idx], hi, lo);
    int nt = n >> 4, kc = k >> 5;
    int l  = ((k >> 3) & 3) * 16 + (n & 15);
    int j  = k & 7;
    long base = ((((long)nt * 16 + kc) * 2) * 64 + l) * 8 + j;
    Wg[base]       = hi;
    Wg[base + 512] = lo;
}

// ---------------------------------------------------------------------------
// GEMM1: support = x @ W1 via split-bf16 MFMA. 128-row tile, BK=64
// single-buffer (R5/R6-verified indexing), 32 KB LDS +
// __launch_bounds__(256,4): 4-5 blocks/CU co-resident -> all 783 blocks in
// ONE occupancy round (was 2 rounds at 1.53 rounds of work with BK=128),
// streaming x at HBM rate with cross-block latency hiding.
// ---------------------------------------------------------------------------
__global__ __launch_bounds__(256, 4) void gemm1_mfma(const float* __restrict__ x,
                                                     const unsigned short* __restrict__ Wg,
                                                     float* __restrict__ support) {
    __shared__ float tile[BM * 64];   // 32 KB

    const int tid  = threadIdx.x;
    const int l    = tid & 63;
    const int w    = tid >> 6;
    const int lr   = l & 15;
    const int lg   = l >> 4;
    const int row0 = blockIdx.x * BM;

    f32x4 acc[2][4] = {};

    for (int kb = 0; kb < F_IN; kb += 64) {
        // --- stage: 128 rows x 16 chunks = 2048 16B slots ---
        #pragma unroll
        for (int j = 0; j < 8; j++) {
            int slotbase = j * 256 + w * 64;        // wave-uniform
            int slot     = slotbase + l;
            int row      = slot >> 4;               // 16 chunks per row
            int cl       = (slot & 15) ^ (row & 7); // inverse swizzle on src
            int rr       = row0 + row;
            if (rr > N_NODES - 1) rr = N_NODES - 1; // clamp (rows >= N discarded)
            gload_lds16(x + (long)rr * F_IN + kb + cl * 4, tile + slotbase * 4);
        }
        __syncthreads();

        #pragma unroll
        for (int ks = 0; ks < 2; ks++) {
            int kc = (kb >> 5) + ks;
            short8 ah[2], al[2];
            #pragma unroll
            for (int m = 0; m < 2; m++) {
                int r  = m * 64 + w * 16 + lr;
                int c0 = ks * 8 + lg * 2;
                f32x4 v0 = *(const f32x4*)&tile[r * 64 + ((c0 ^ (r & 7)) << 2)];
                f32x4 v1 = *(const f32x4*)&tile[r * 64 + (((c0 + 1) ^ (r & 7)) << 2)];
                split8(v0, v1, ah[m], al[m]);
            }
            #pragma unroll
            for (int nt = 0; nt < 4; nt++) {
                long bo = ((((long)nt * 16 + kc) * 2) * 64 + l) * 8;
                short8 bh = *(const short8*)(Wg + bo);
                short8 bl = *(const short8*)(Wg + bo + 512);
                #pragma unroll
                for (int m = 0; m < 2; m++) {
                    acc[m][nt] = __builtin_amdgcn_mfma_f32_16x16x32_bf16(ah[m], bh, acc[m][nt], 0, 0, 0);
                    acc[m][nt] = __builtin_amdgcn_mfma_f32_16x16x32_bf16(ah[m], bl, acc[m][nt], 0, 0, 0);
                    acc[m][nt] = __builtin_amdgcn_mfma_f32_16x16x32_bf16(al[m], bh, acc[m][nt], 0, 0, 0);
                }
            }
        }
        __syncthreads();
    }

    // epilogue: C/D layout col = lane&15, row = (lane>>4)*4 + reg
    #pragma unroll
    for (int m = 0; m < 2; m++) {
        #pragma unroll
        for (int nt = 0; nt < 4; nt++) {
            #pragma unroll
            for (int r = 0; r < 4; r++) {
                int row = row0 + m * 64 + w * 16 + lg * 4 + r;
                if (row < N_NODES)
                    support[(long)row * HID + nt * 16 + lr] = acc[m][nt][r];
            }
        }
    }
}

// ---------------------------------------------------------------------------
// SPMM1 + bias + relu + GEMM2 fused (R10-PROVEN): grid-stride, one wave per
// node, float1 full-row gathers, 8/4/1 cascade. W2 staged once per block.
// ---------------------------------------------------------------------------
__global__ __launch_bounds__(256) void spmm1_fused(const int* __restrict__ off,
                                                   const int2* __restrict__ epk,
                                                   const float* __restrict__ sup,
                                                   const float* __restrict__ b1,
                                                   const float* __restrict__ W2,
                                                   float* __restrict__ sup2) {
    __shared__ float w2s[HID * NCLS];   // [k][c]
    __shared__ float hrow[2][4][HID];
    int tid = threadIdx.x;
    for (int i = tid; i < HID * NCLS; i += 256) w2s[i] = W2[i];
    __syncthreads();

    int lane = tid & 63;
    int w    = tid >> 6;
    int c    = lane & 15, q = lane >> 4;
    float bl = b1[lane];

    for (int g = blockIdx.x; g < N_NODES / 4; g += gridDim.x) {
        int n = g * 4 + w;              // N_NODES % 4 == 0
        int e0 = off[n];
        int e1 = off[n + 1];
        float acc = 0.f;
        int e = e0;
        for (; e + 7 < e1; e += 8) {
            int2 p[8];
            float gg[8];
            #pragma unroll
            for (int j = 0; j < 8; j++) p[j] = epk[e + j];
            #pragma unroll
            for (int j = 0; j < 8; j++) gg[j] = sup[(long)p[j].x * HID + lane];
            #pragma unroll
            for (int j = 0; j < 8; j++) acc += __int_as_float(p[j].y) * gg[j];
        }
        for (; e + 3 < e1; e += 4) {
            int2 p0 = epk[e],     p1 = epk[e + 1];
            int2 p2 = epk[e + 2], p3 = epk[e + 3];
            float g0 = sup[(long)p0.x * HID + lane];
            float g1 = sup[(long)p1.x * HID + lane];
            float g2 = sup[(long)p2.x * HID + lane];
            float g3 = sup[(long)p3.x * HID + lane];
            acc += __int_as_float(p0.y) * g0 + __int_as_float(p1.y) * g1
                 + __int_as_float(p2.y) * g2 + __int_as_float(p3.y) * g3;
        }
        for (; e < e1; e++) {
            int2 p = epk[e];
            acc += __int_as_float(p.y) * sup[(long)p.x * HID + lane];
        }
        float hv = fmaxf(acc + bl, 0.f);

        int par = g & 1;
        hrow[par][w][lane] = hv;
        asm volatile("s_waitcnt lgkmcnt(0)" ::: "memory");   // wave-local drain
        __builtin_amdgcn_sched_barrier(0);                   // rule #18 fence

        float part = 0.f;
        #pragma unroll
        for (int k0 = 0; k0 < 16; k0++) {
            int k = q * 16 + k0;
            part += hrow[par][w][k] * w2s[k * NCLS + c];
        }
        part += __shfl_xor(part, 16);
        part += __shfl_xor(part, 32);
        if (lane < 16) sup2[(long)n * NCLS + c] = part;
    }
}

// ---------------------------------------------------------------------------
// SPMM2 (CSR) fused with +b2 and softmax (R10-PROVEN one-shot form).
// 16 lanes per node, 8/4/1 cascade gathers.
// ---------------------------------------------------------------------------
__global__ __launch_bounds__(256) void spmm2_softmax(const int* __restrict__ off,
                                                     const int2* __restrict__ epk,
                                                     const float* __restrict__ sup2,
                                                     const float* __restrict__ b2,
                                                     float* __restrict__ out) {
    int tid = threadIdx.x;
    int n   = blockIdx.x * 16 + (tid >> 4);
    int c   = tid & 15;
    if (n >= N_NODES) return;

    int e0 = off[n];
    int e1 = off[n + 1];
    float acc = 0.f;
    int e = e0;
    for (; e + 7 < e1; e += 8) {
        int2 p[8];
        float g[8];
        #pragma unroll
        for (int j = 0; j < 8; j++) p[j] = epk[e + j];
        #pragma unroll
        for (int j = 0; j < 8; j++) g[j] = sup2[(long)p[j].x * NCLS + c];
        #pragma unroll
        for (int j = 0; j < 8; j++) acc += __int_as_float(p[j].y) * g[j];
    }
    for (; e + 3 < e1; e += 4) {
        int2 p0 = epk[e],     p1 = epk[e + 1];
        int2 p2 = epk[e + 2], p3 = epk[e + 3];
        float g0 = sup2[(long)p0.x * NCLS + c];
        float g1 = sup2[(long)p1.x * NCLS + c];
        float g2 = sup2[(long)p2.x * NCLS + c];
        float g3 = sup2[(long)p3.x * NCLS + c];
        acc += __int_as_float(p0.y) * g0 + __int_as_float(p1.y) * g1
             + __int_as_float(p2.y) * g2 + __int_as_float(p3.y) * g3;
    }
    for (; e < e1; e++) {
        int2 p = epk[e];
        acc += __int_as_float(p.y) * sup2[(long)p.x * NCLS + c];
    }

    float lg = acc + b2[c];
    float m = lg;
    #pragma unroll
    for (int mask = 1; mask < 16; mask <<= 1)
        m = fmaxf(m, __shfl_xor(m, mask, 16));
    float p = expf(lg - m);
    float s = p;
    #pragma unroll
    for (int mask = 1; mask < 16; mask <<= 1)
        s += __shfl_xor(s, mask, 16);
    out[(long)n * NCLS + c] = p / s;
}

// ---------------------------------------------------------------------------
extern "C" void kernel_launch(void* const* d_in, const int* in_sizes, int n_in,
                              void* d_out, int out_size, void* d_ws, size_t ws_size,
                              hipStream_t stream) {
    const float* x     = (const float*)d_in[0];
    const int*   esrc  = (const int*)  d_in[1];
    const int*   edst  = (const int*)  d_in[2];
    const float* eval_ = (const float*)d_in[3];
    const float* W1    = (const float*)d_in[4];
    const float* b1    = (const float*)d_in[5];
    const float* W2    = (const float*)d_in[6];
    const float* b2    = (const float*)d_in[7];
    float* out = (float*)d_out;

    // workspace layout (4B units; every base 16B-aligned)
    float* sup1  = (float*)d_ws;                        // 6,400,000 f
    float* sup2  = sup1 + (long)N_NODES * HID;          // 1,600,000 f
    int2*  epk   = (int2*)(sup2 + (long)N_NODES * NCLS);// 1,600,000 int2
    int*   off   = (int*)(epk + N_EDGES);               // 100,004 i
    int*   bsums = off + 100004;                        // 128 i
    int*   bbase = bsums + 128;                         // 128 i
    int*   bh    = bbase + 128;                         // 38,320 i (98x391)
    unsigned short* Wg = (unsigned short*)(bh + 38320); // 65,536 us (128 KB)
    int2*  mid   = (int2*)(Wg + 65536);                 // 1,600,000 int2

    // --- CSR build (scan-based, no global atomics) ---
    bhist  <<<PA_NB,   256, 0, stream>>>(edst, bh);
    colscan<<<SCAN_NB, 512, 0, stream>>>(bh, bsums);
    scan_top<<<1,      128, 0, stream>>>(bsums, bbase, off);
    partA2 <<<PA_NB,   256, 0, stream>>>(esrc, edst, eval_, bh, bbase, mid);
    partB2 <<<SCAN_NB, 512, 0, stream>>>(bbase, bsums, mid, epk, off);

    // --- W1 fragment prep + layer 1 ---
    prep_w1<<<(F_IN * HID + 255) / 256, 256, 0, stream>>>(W1, Wg);
    gemm1_mfma<<<(N_NODES + BM - 1) / BM, 256, 0, stream>>>(x, Wg, sup1);
    spmm1_fused<<<4096, 256, 0, stream>>>(off, epk, sup1, b1, W2, sup2);

    // --- layer 2 + softmax ---
    spmm2_softmax<<<(N_NODES + 15) / 16, 256, 0, stream>>>(off, epk, sup2, b2, out);
}

// Round 14
// 219.789 us; speedup vs baseline: 1.0433x; 1.0433x over previous
//
#include <hip/hip_runtime.h>
#include <hip/hip_bf16.h>

#define N_NODES 100000
#define N_EDGES 1600000
#define F_IN    512
#define HID     64
#define NCLS    16

#define SCAN_NB 98      // ceil(100000 / 1024) = # of 1024-node buckets
#define BM      128     // gemm1 row tile
#define BK      128     // gemm1 k tile
#define PA_EPB  4096    // partition edges per block
#define PA_NB   ((N_EDGES + PA_EPB - 1) / PA_EPB)   // 391
#define PREP_NB 128     // prep_w1 blocks fused behind bhist

typedef __attribute__((ext_vector_type(8))) short short8;
typedef __attribute__((ext_vector_type(4))) float f32x4;
typedef unsigned int u32;
typedef unsigned short u16;

// ---------------------------------------------------------------------------
// async global->LDS 16B (wave-uniform LDS base + lane*16 dest semantics)
// ---------------------------------------------------------------------------
__device__ inline void gload_lds16(const float* g, float* l) {
    __builtin_amdgcn_global_load_lds(
        (const __attribute__((address_space(1))) u32*)g,
        (__attribute__((address_space(3))) u32*)l, 16, 0, 0);
}

// ---------------------------------------------------------------------------
// split fp32 -> bf16 hi + bf16 lo (truncation; residual ~2^-16 relative)
// ---------------------------------------------------------------------------
__device__ inline void split_bf16(float a, unsigned short& hi, unsigned short& lo) {
    unsigned u = __float_as_uint(a);
    hi = (unsigned short)(u >> 16);
    float hif = __uint_as_float(((unsigned)hi) << 16);
    float lof = a - hif;
    lo = (unsigned short)(__float_as_uint(lof) >> 16);
}

// split 8 fp32 (two f32x4) into hi/lo short8 fragments
__device__ inline void split8(f32x4 a, f32x4 b, short8& hi, short8& lo) {
    #pragma unroll
    for (int i = 0; i < 4; i++) {
        u16 h, l;
        split_bf16(a[i], h, l);
        hi[i] = (short)h; lo[i] = (short)l;
    }
    #pragma unroll
    for (int i = 0; i < 4; i++) {
        u16 h, l;
        split_bf16(b[i], h, l);
        hi[4 + i] = (short)h; lo[4 + i] = (short)l;
    }
}

// ---------------------------------------------------------------------------
// FUSED CSR build 1 + W1 prep (disjoint block ranges, disjoint in/out):
//  blocks [0, PA_NB):          per-block bucket histogram -> bh[bucket][blk]
//  blocks [PA_NB, PA_NB+128):  W1 [512][64] fp32 -> Wg fragment-native
//                              bf16 hi/lo (lane l: n=nt*16+(l&15),
//                              k=kc*32+(l>>4)*8+j)
// ---------------------------------------------------------------------------
__global__ __launch_bounds__(256) void bhist_prep(const int* __restrict__ edst,
                                                  int* __restrict__ bh,
                                                  const float* __restrict__ W1,
                                                  unsigned short* __restrict__ Wg) {
    int tid = threadIdx.x;
    if (blockIdx.x >= PA_NB) {
        // --- prep_w1 role ---
        int idx = (blockIdx.x - PA_NB) * 256 + tid;   // 0 .. 32767
        if (idx < F_IN * HID) {
            int k = idx >> 6, n = idx & 63;
            unsigned short hi, lo;
            split_bf16(W1[idx], hi, lo);
            int nt = n >> 4, kc = k >> 5;
            int l  = ((k >> 3) & 3) * 16 + (n & 15);
            int j  = k & 7;
            long base = ((((long)nt * 16 + kc) * 2) * 64 + l) * 8 + j;
            Wg[base]       = hi;
            Wg[base + 512] = lo;
        }
        return;
    }
    // --- bhist role ---
    __shared__ int hist[SCAN_NB];
    int e00 = blockIdx.x * PA_EPB;
    for (int i = tid; i < SCAN_NB; i += 256) hist[i] = 0;
    __syncthreads();
    #pragma unroll
    for (int j = 0; j < PA_EPB / 256; j++) {
        int e = e00 + j * 256 + tid;
        if (e < N_EDGES) atomicAdd(&hist[edst[e] >> 10], 1);
    }
    __syncthreads();
    for (int i = tid; i < SCAN_NB; i += 256)
        bh[i * PA_NB + blockIdx.x] = hist[i];
}

// ---------------------------------------------------------------------------
// CSR build 2: per bucket, exclusive scan over the 391 block counts
// ---------------------------------------------------------------------------
__global__ __launch_bounds__(512) void colscan(int* __restrict__ bh,
                                               int* __restrict__ bsums) {
    __shared__ int sc[512];
    int t = threadIdx.x;
    int b = blockIdx.x;
    int v = (t < PA_NB) ? bh[b * PA_NB + t] : 0;
    sc[t] = v;
    __syncthreads();
    #pragma unroll
    for (int d = 1; d < 512; d <<= 1) {
        int u = (t >= d) ? sc[t - d] : 0;
        __syncthreads();
        sc[t] += u;
        __syncthreads();
    }
    if (t < PA_NB) bh[b * PA_NB + t] = sc[t] - v;   // exclusive
    if (t == 511) bsums[b] = sc[511];
}

// ---------------------------------------------------------------------------
// CSR build 3: exclusive scan of bucket sums -> bbase; off[N]=E.
// ---------------------------------------------------------------------------
__global__ __launch_bounds__(128) void scan_top(const int* __restrict__ bsums,
                                                int* __restrict__ bbase,
                                                int* __restrict__ off) {
    __shared__ int sc[128];
    int t = threadIdx.x;
    int v0 = (t < SCAN_NB) ? bsums[t] : 0;
    sc[t] = v0;
    __syncthreads();
    #pragma unroll
    for (int d = 1; d < 128; d <<= 1) {
        int v = (t >= d) ? sc[t - d] : 0;
        __syncthreads();
        sc[t] += v;
        __syncthreads();
    }
    bbase[t] = sc[t] - v0;
    if (t == 0) off[N_NODES] = N_EDGES;
}

// ---------------------------------------------------------------------------
// CSR build 4: bucket edges by dst>>10 into mid[]; deterministic
// reservations (bbase + scanned blockhist); LDS cursors only.
// mid.x packs src (17b) | dst_low10 << 17 ; mid.y = val bits.
// ---------------------------------------------------------------------------
__global__ __launch_bounds__(256) void partA2(const int* __restrict__ esrc,
                                              const int* __restrict__ edst,
                                              const float* __restrict__ eval_,
                                              const int* __restrict__ bh,
                                              const int* __restrict__ bbase,
                                              int2* __restrict__ mid) {
    __shared__ int curs[SCAN_NB];
    int tid = threadIdx.x;
    int blk = blockIdx.x;
    int e00 = blk * PA_EPB;
    for (int i = tid; i < SCAN_NB; i += 256)
        curs[i] = bbase[i] + bh[i * PA_NB + blk];
    __syncthreads();
    #pragma unroll
    for (int j = 0; j < PA_EPB / 256; j++) {
        int e = e00 + j * 256 + tid;
        if (e < N_EDGES) {
            int d = edst[e];
            int b = d >> 10;
            int pos = atomicAdd(&curs[b], 1);
            mid[pos] = make_int2(esrc[e] | ((d & 1023) << 17),
                                 __float_as_int(eval_[e]));
        }
    }
}

// ---------------------------------------------------------------------------
// CSR build 5: within-bucket final scatter; node degrees + LDS scan ->
// off[] and cursors locally; zero global atomics.
// ---------------------------------------------------------------------------
__global__ __launch_bounds__(512) void partB2(const int* __restrict__ bbase,
                                              const int* __restrict__ bsums,
                                              const int2* __restrict__ mid,
                                              int2* __restrict__ epk,
                                              int* __restrict__ off) {
    __shared__ int nh[1024];
    __shared__ int sc[512];
    int t = threadIdx.x;
    int b = blockIdx.x;
    int start = bbase[b];
    int cntb  = bsums[b];

    nh[t] = 0; nh[t + 512] = 0;
    __syncthreads();

    for (int i = t; i < cntb; i += 512) {
        u32 ux = (u32)mid[start + i].x;
        atomicAdd(&nh[ux >> 17], 1);
    }
    __syncthreads();

    int c0 = nh[2 * t], c1 = nh[2 * t + 1];
    int s = c0 + c1;
    sc[t] = s;
    __syncthreads();
    #pragma unroll
    for (int d = 1; d < 512; d <<= 1) {
        int u = (t >= d) ? sc[t - d] : 0;
        __syncthreads();
        sc[t] += u;
        __syncthreads();
    }
    int ex = start + sc[t] - s;

    nh[2 * t]     = ex;
    nh[2 * t + 1] = ex + c0;
    int node = (b << 10) + 2 * t;
    if (node < N_NODES)     off[node]     = ex;
    if (node + 1 < N_NODES) off[node + 1] = ex + c0;
    __syncthreads();

    for (int i = t; i < cntb; i += 512) {
        int2 m = mid[start + i];
        u32 ux = (u32)m.x;
        int pos = atomicAdd(&nh[ux >> 17], 1);
        epk[pos] = make_int2((int)(ux & 0x1FFFF), m.y);
    }
}

// ---------------------------------------------------------------------------
// GEMM1 (R8/R10-proven): support = x @ W1 via split-bf16 MFMA. 128-row tile,
// BK=128 single-buffer (one barrier pair per 128 K), __launch_bounds__(256,2).
// ---------------------------------------------------------------------------
__global__ __launch_bounds__(256, 2) void gemm1_mfma(const float* __restrict__ x,
                                                     const unsigned short* __restrict__ Wg,
                                                     float* __restrict__ support) {
    __shared__ float tile[BM * BK];   // 64 KB

    const int tid  = threadIdx.x;
    const int l    = tid & 63;
    const int w    = tid >> 6;
    const int lr   = l & 15;
    const int lg   = l >> 4;
    const int row0 = blockIdx.x * BM;

    f32x4 acc[2][4] = {};

    for (int kb = 0; kb < F_IN; kb += BK) {
        // --- stage: 128 rows x 32 chunks = 4096 16B slots ---
        #pragma unroll
        for (int j = 0; j < 16; j++) {
            int slotbase = j * 256 + w * 64;        // wave-uniform
            int slot     = slotbase + l;
            int row      = slot >> 5;               // 32 chunks per row
            int cl       = (slot & 31) ^ (row & 7); // inverse swizzle on src
            int rr       = row0 + row;
            if (rr > N_NODES - 1) rr = N_NODES - 1; // clamp (rows >= N discarded)
            gload_lds16(x + (long)rr * F_IN + kb + cl * 4, tile + slotbase * 4);
        }
        __syncthreads();

        #pragma unroll
        for (int ks = 0; ks < 4; ks++) {
            int kc = (kb >> 5) + ks;
            short8 ah[2], al[2];
            #pragma unroll
            for (int m = 0; m < 2; m++) {
                int r  = m * 64 + w * 16 + lr;
                int c0 = ks * 8 + lg * 2;
                f32x4 v0 = *(const f32x4*)&tile[r * BK + ((c0 ^ (r & 7)) << 2)];
                f32x4 v1 = *(const f32x4*)&tile[r * BK + (((c0 + 1) ^ (r & 7)) << 2)];
                split8(v0, v1, ah[m], al[m]);
            }
            #pragma unroll
            for (int nt = 0; nt < 4; nt++) {
                long bo = ((((long)nt * 16 + kc) * 2) * 64 + l) * 8;
                short8 bh = *(const short8*)(Wg + bo);
                short8 bl = *(const short8*)(Wg + bo + 512);
                #pragma unroll
                for (int m = 0; m < 2; m++) {
                    acc[m][nt] = __builtin_amdgcn_mfma_f32_16x16x32_bf16(ah[m], bh, acc[m][nt], 0, 0, 0);
                    acc[m][nt] = __builtin_amdgcn_mfma_f32_16x16x32_bf16(ah[m], bl, acc[m][nt], 0, 0, 0);
                    acc[m][nt] = __builtin_amdgcn_mfma_f32_16x16x32_bf16(al[m], bh, acc[m][nt], 0, 0, 0);
                }
            }
        }
        __syncthreads();
    }

    // epilogue: C/D layout col = lane&15, row = (lane>>4)*4 + reg
    #pragma unroll
    for (int m = 0; m < 2; m++) {
        #pragma unroll
        for (int nt = 0; nt < 4; nt++) {
            #pragma unroll
            for (int r = 0; r < 4; r++) {
                int row = row0 + m * 64 + w * 16 + lg * 4 + r;
                if (row < N_NODES)
                    support[(long)row * HID + nt * 16 + lr] = acc[m][nt][r];
            }
        }
    }
}

// ---------------------------------------------------------------------------
// SPMM1 + bias + relu + GEMM2 fused (R10-PROVEN): grid-stride, one wave per
// node, float1 full-row gathers, 8/4/1 cascade. W2 staged once per block.
// ---------------------------------------------------------------------------
__global__ __launch_bounds__(256) void spmm1_fused(const int* __restrict__ off,
                                                   const int2* __restrict__ epk,
                                                   const float* __restrict__ sup,
                                                   const float* __restrict__ b1,
                                                   const float* __restrict__ W2,
                                                   float* __restrict__ sup2) {
    __shared__ float w2s[HID * NCLS];   // [k][c]
    __shared__ float hrow[2][4][HID];
    int tid = threadIdx.x;
    for (int i = tid; i < HID * NCLS; i += 256) w2s[i] = W2[i];
    __syncthreads();

    int lane = tid & 63;
    int w    = tid >> 6;
    int c    = lane & 15, q = lane >> 4;
    float bl = b1[lane];

    for (int g = blockIdx.x; g < N_NODES / 4; g += gridDim.x) {
        int n = g * 4 + w;              // N_NODES % 4 == 0
        int e0 = off[n];
        int e1 = off[n + 1];
        float acc = 0.f;
        int e = e0;
        for (; e + 7 < e1; e += 8) {
            int2 p[8];
            float gg[8];
            #pragma unroll
            for (int j = 0; j < 8; j++) p[j] = epk[e + j];
            #pragma unroll
            for (int j = 0; j < 8; j++) gg[j] = sup[(long)p[j].x * HID + lane];
            #pragma unroll
            for (int j = 0; j < 8; j++) acc += __int_as_float(p[j].y) * gg[j];
        }
        for (; e + 3 < e1; e += 4) {
            int2 p0 = epk[e],     p1 = epk[e + 1];
            int2 p2 = epk[e + 2], p3 = epk[e + 3];
            float g0 = sup[(long)p0.x * HID + lane];
            float g1 = sup[(long)p1.x * HID + lane];
            float g2 = sup[(long)p2.x * HID + lane];
            float g3 = sup[(long)p3.x * HID + lane];
            acc += __int_as_float(p0.y) * g0 + __int_as_float(p1.y) * g1
                 + __int_as_float(p2.y) * g2 + __int_as_float(p3.y) * g3;
        }
        for (; e < e1; e++) {
            int2 p = epk[e];
            acc += __int_as_float(p.y) * sup[(long)p.x * HID + lane];
        }
        float hv = fmaxf(acc + bl, 0.f);

        int par = g & 1;
        hrow[par][w][lane] = hv;
        asm volatile("s_waitcnt lgkmcnt(0)" ::: "memory");   // wave-local drain
        __builtin_amdgcn_sched_barrier(0);                   // rule #18 fence

        float part = 0.f;
        #pragma unroll
        for (int k0 = 0; k0 < 16; k0++) {
            int k = q * 16 + k0;
            part += hrow[par][w][k] * w2s[k * NCLS + c];
        }
        part += __shfl_xor(part, 16);
        part += __shfl_xor(part, 32);
        if (lane < 16) sup2[(long)n * NCLS + c] = part;
    }
}

// ---------------------------------------------------------------------------
// SPMM2 (CSR) fused with +b2 and softmax (R10-PROVEN one-shot form).
// 16 lanes per node, 8/4/1 cascade gathers.
// ---------------------------------------------------------------------------
__global__ __launch_bounds__(256) void spmm2_softmax(const int* __restrict__ off,
                                                     const int2* __restrict__ epk,
                                                     const float* __restrict__ sup2,
                                                     const float* __restrict__ b2,
                                                     float* __restrict__ out) {
    int tid = threadIdx.x;
    int n   = blockIdx.x * 16 + (tid >> 4);
    int c   = tid & 15;
    if (n >= N_NODES) return;

    int e0 = off[n];
    int e1 = off[n + 1];
    float acc = 0.f;
    int e = e0;
    for (; e + 7 < e1; e += 8) {
        int2 p[8];
        float g[8];
        #pragma unroll
        for (int j = 0; j < 8; j++) p[j] = epk[e + j];
        #pragma unroll
        for (int j = 0; j < 8; j++) g[j] = sup2[(long)p[j].x * NCLS + c];
        #pragma unroll
        for (int j = 0; j < 8; j++) acc += __int_as_float(p[j].y) * g[j];
    }
    for (; e + 3 < e1; e += 4) {
        int2 p0 = epk[e],     p1 = epk[e + 1];
        int2 p2 = epk[e + 2], p3 = epk[e + 3];
        float g0 = sup2[(long)p0.x * NCLS + c];
        float g1 = sup2[(long)p1.x * NCLS + c];
        float g2 = sup2[(long)p2.x * NCLS + c];
        float g3 = sup2[(long)p3.x * NCLS + c];
        acc += __int_as_float(p0.y) * g0 + __int_as_float(p1.y) * g1
             + __int_as_float(p2.y) * g2 + __int_as_float(p3.y) * g3;
    }
    for (; e < e1; e++) {
        int2 p = epk[e];
        acc += __int_as_float(p.y) * sup2[(long)p.x * NCLS + c];
    }

    float lg = acc + b2[c];
    float m = lg;
    #pragma unroll
    for (int mask = 1; mask < 16; mask <<= 1)
        m = fmaxf(m, __shfl_xor(m, mask, 16));
    float p = expf(lg - m);
    float s = p;
    #pragma unroll
    for (int mask = 1; mask < 16; mask <<= 1)
        s += __shfl_xor(s, mask, 16);
    out[(long)n * NCLS + c] = p / s;
}

// ---------------------------------------------------------------------------
extern "C" void kernel_launch(void* const* d_in, const int* in_sizes, int n_in,
                              void* d_out, int out_size, void* d_ws, size_t ws_size,
                              hipStream_t stream) {
    const float* x     = (const float*)d_in[0];
    const int*   esrc  = (const int*)  d_in[1];
    const int*   edst  = (const int*)  d_in[2];
    const float* eval_ = (const float*)d_in[3];
    const float* W1    = (const float*)d_in[4];
    const float* b1    = (const float*)d_in[5];
    const float* W2    = (const float*)d_in[6];
    const float* b2    = (const float*)d_in[7];
    float* out = (float*)d_out;

    // workspace layout (4B units; every base 16B-aligned)
    float* sup1  = (float*)d_ws;                        // 6,400,000 f
    float* sup2  = sup1 + (long)N_NODES * HID;          // 1,600,000 f
    int2*  epk   = (int2*)(sup2 + (long)N_NODES * NCLS);// 1,600,000 int2
    int*   off   = (int*)(epk + N_EDGES);               // 100,004 i
    int*   bsums = off + 100004;                        // 128 i
    int*   bbase = bsums + 128;                         // 128 i
    int*   bh    = bbase + 128;                         // 38,320 i (98x391)
    unsigned short* Wg = (unsigned short*)(bh + 38320); // 65,536 us (128 KB)
    int2*  mid   = (int2*)(Wg + 65536);                 // 1,600,000 int2

    // --- CSR build (scan-based, no global atomics) + fused W1 prep ---
    bhist_prep<<<PA_NB + PREP_NB, 256, 0, stream>>>(edst, bh, W1, Wg);
    colscan<<<SCAN_NB, 512, 0, stream>>>(bh, bsums);
    scan_top<<<1,      128, 0, stream>>>(bsums, bbase, off);
    partA2 <<<PA_NB,   256, 0, stream>>>(esrc, edst, eval_, bh, bbase, mid);
    partB2 <<<SCAN_NB, 512, 0, stream>>>(bbase, bsums, mid, epk, off);

    // --- layer 1 ---
    gemm1_mfma<<<(N_NODES + BM - 1) / BM, 256, 0, stream>>>(x, Wg, sup1);
    spmm1_fused<<<4096, 256, 0, stream>>>(off, epk, sup1, b1, W2, sup2);

    // --- layer 2 + softmax ---
    spmm2_softmax<<<(N_NODES + 15) / 16, 256, 0, stream>>>(off, epk, sup2, b2, out);
}

// Round 15
// 204.827 us; speedup vs baseline: 1.1195x; 1.0730x over previous
//
#include <hip/hip_runtime.h>
#include <hip/hip_bf16.h>

#define N_NODES 100000
#define N_EDGES 1600000
#define F_IN    512
#define HID     64
#define NCLS    16

#define SCAN_NB 98      // ceil(100000 / 1024) = # of 1024-node buckets
#define BM      128     // gemm1 row tile
#define BK      128     // gemm1 k tile
#define PA_EPB  4096    // partition edges per block
#define PA_NB   ((N_EDGES + PA_EPB - 1) / PA_EPB)   // 391
#define PREP_NB 128     // prep_w1 blocks fused behind bhist
#define GEMM_NB ((N_NODES + BM - 1) / BM)           // 782

typedef __attribute__((ext_vector_type(8))) short short8;
typedef __attribute__((ext_vector_type(4))) float f32x4;
typedef unsigned int u32;
typedef unsigned short u16;

// ---------------------------------------------------------------------------
// async global->LDS 16B (wave-uniform LDS base + lane*16 dest semantics)
// ---------------------------------------------------------------------------
__device__ inline void gload_lds16(const float* g, float* l) {
    __builtin_amdgcn_global_load_lds(
        (const __attribute__((address_space(1))) u32*)g,
        (__attribute__((address_space(3))) u32*)l, 16, 0, 0);
}

// ---------------------------------------------------------------------------
// split fp32 -> bf16 hi + bf16 lo (truncation; residual ~2^-16 relative)
// ---------------------------------------------------------------------------
__device__ inline void split_bf16(float a, unsigned short& hi, unsigned short& lo) {
    unsigned u = __float_as_uint(a);
    hi = (unsigned short)(u >> 16);
    float hif = __uint_as_float(((unsigned)hi) << 16);
    float lof = a - hif;
    lo = (unsigned short)(__float_as_uint(lof) >> 16);
}

// split 8 fp32 (two f32x4) into hi/lo short8 fragments
__device__ inline void split8(f32x4 a, f32x4 b, short8& hi, short8& lo) {
    #pragma unroll
    for (int i = 0; i < 4; i++) {
        u16 h, l;
        split_bf16(a[i], h, l);
        hi[i] = (short)h; lo[i] = (short)l;
    }
    #pragma unroll
    for (int i = 0; i < 4; i++) {
        u16 h, l;
        split_bf16(b[i], h, l);
        hi[4 + i] = (short)h; lo[4 + i] = (short)l;
    }
}

// ---------------------------------------------------------------------------
// FUSED CSR build 1 + W1 prep (disjoint block ranges, disjoint in/out):
//  blocks [0, PA_NB):          per-block bucket histogram -> bh[bucket][blk]
//  blocks [PA_NB, PA_NB+128):  W1 [512][64] fp32 -> Wg fragment-native
//                              bf16 hi/lo
// ---------------------------------------------------------------------------
__global__ __launch_bounds__(256) void bhist_prep(const int* __restrict__ edst,
                                                  int* __restrict__ bh,
                                                  const float* __restrict__ W1,
                                                  unsigned short* __restrict__ Wg) {
    int tid = threadIdx.x;
    if (blockIdx.x >= PA_NB) {
        // --- prep_w1 role ---
        int idx = (blockIdx.x - PA_NB) * 256 + tid;   // 0 .. 32767
        if (idx < F_IN * HID) {
            int k = idx >> 6, n = idx & 63;
            unsigned short hi, lo;
            split_bf16(W1[idx], hi, lo);
            int nt = n >> 4, kc = k >> 5;
            int l  = ((k >> 3) & 3) * 16 + (n & 15);
            int j  = k & 7;
            long base = ((((long)nt * 16 + kc) * 2) * 64 + l) * 8 + j;
            Wg[base]       = hi;
            Wg[base + 512] = lo;
        }
        return;
    }
    // --- bhist role ---
    __shared__ int hist[SCAN_NB];
    int e00 = blockIdx.x * PA_EPB;
    for (int i = tid; i < SCAN_NB; i += 256) hist[i] = 0;
    __syncthreads();
    #pragma unroll
    for (int j = 0; j < PA_EPB / 256; j++) {
        int e = e00 + j * 256 + tid;
        if (e < N_EDGES) atomicAdd(&hist[edst[e] >> 10], 1);
    }
    __syncthreads();
    for (int i = tid; i < SCAN_NB; i += 256)
        bh[i * PA_NB + blockIdx.x] = hist[i];
}

// ---------------------------------------------------------------------------
// CSR build 2: per bucket, exclusive scan over the 391 block counts
// ---------------------------------------------------------------------------
__global__ __launch_bounds__(512) void colscan(int* __restrict__ bh,
                                               int* __restrict__ bsums) {
    __shared__ int sc[512];
    int t = threadIdx.x;
    int b = blockIdx.x;
    int v = (t < PA_NB) ? bh[b * PA_NB + t] : 0;
    sc[t] = v;
    __syncthreads();
    #pragma unroll
    for (int d = 1; d < 512; d <<= 1) {
        int u = (t >= d) ? sc[t - d] : 0;
        __syncthreads();
        sc[t] += u;
        __syncthreads();
    }
    if (t < PA_NB) bh[b * PA_NB + t] = sc[t] - v;   // exclusive
    if (t == 511) bsums[b] = sc[511];
}

// ---------------------------------------------------------------------------
// CSR build 3: exclusive scan of bucket sums -> bbase; off[N]=E.
// ---------------------------------------------------------------------------
__global__ __launch_bounds__(128) void scan_top(const int* __restrict__ bsums,
                                                int* __restrict__ bbase,
                                                int* __restrict__ off) {
    __shared__ int sc[128];
    int t = threadIdx.x;
    int v0 = (t < SCAN_NB) ? bsums[t] : 0;
    sc[t] = v0;
    __syncthreads();
    #pragma unroll
    for (int d = 1; d < 128; d <<= 1) {
        int v = (t >= d) ? sc[t - d] : 0;
        __syncthreads();
        sc[t] += v;
        __syncthreads();
    }
    bbase[t] = sc[t] - v0;
    if (t == 0) off[N_NODES] = N_EDGES;
}

// ---------------------------------------------------------------------------
// FUSED partA2 + GEMM1 (disjoint block ranges, disjoint inputs/outputs,
// no cross-role ordering assumptions):
//  blocks [0, PA_NB):  partA2 — bucket edges by dst>>10 into mid[] via
//      deterministic reservations (bbase + scanned blockhist), LDS cursors.
//      Placed FIRST in dispatch order so they co-run with early gemm blocks
//      and drain quickly (~10 us of L2-bound scatter hidden under gemm).
//  blocks [PA_NB, PA_NB+GEMM_NB):  gemm1 (R8/R10-proven) — support = x @ W1
//      via split-bf16 MFMA, 128-row tile, BK=128 single-buffer.
// Static LDS = 64 KB (tile) + 0.4 KB (curs) -> 2 blocks/CU, as gemm1 had.
// ---------------------------------------------------------------------------
__global__ __launch_bounds__(256, 2) void partA_gemm1(
        const int* __restrict__ esrc, const int* __restrict__ edst,
        const float* __restrict__ eval_, const int* __restrict__ bh,
        const int* __restrict__ bbase, int2* __restrict__ mid,
        const float* __restrict__ x, const unsigned short* __restrict__ Wg,
        float* __restrict__ support) {
    __shared__ float tile[BM * BK];   // 64 KB (gemm role)
    __shared__ int   curs[SCAN_NB];   // partA role

    const int tid = threadIdx.x;

    if (blockIdx.x < PA_NB) {
        // ---------------- partA2 role ----------------
        int blk = blockIdx.x;
        int e00 = blk * PA_EPB;
        for (int i = tid; i < SCAN_NB; i += 256)
            curs[i] = bbase[i] + bh[i * PA_NB + blk];
        __syncthreads();
        #pragma unroll
        for (int j = 0; j < PA_EPB / 256; j++) {
            int e = e00 + j * 256 + tid;
            if (e < N_EDGES) {
                int d = edst[e];
                int b = d >> 10;
                int pos = atomicAdd(&curs[b], 1);
                mid[pos] = make_int2(esrc[e] | ((d & 1023) << 17),
                                     __float_as_int(eval_[e]));
            }
        }
        return;
    }

    // ---------------- gemm1 role ----------------
    const int l    = tid & 63;
    const int w    = tid >> 6;
    const int lr   = l & 15;
    const int lg   = l >> 4;
    const int row0 = (blockIdx.x - PA_NB) * BM;

    f32x4 acc[2][4] = {};

    for (int kb = 0; kb < F_IN; kb += BK) {
        // --- stage: 128 rows x 32 chunks = 4096 16B slots ---
        #pragma unroll
        for (int j = 0; j < 16; j++) {
            int slotbase = j * 256 + w * 64;        // wave-uniform
            int slot     = slotbase + l;
            int row      = slot >> 5;               // 32 chunks per row
            int cl       = (slot & 31) ^ (row & 7); // inverse swizzle on src
            int rr       = row0 + row;
            if (rr > N_NODES - 1) rr = N_NODES - 1; // clamp (rows >= N discarded)
            gload_lds16(x + (long)rr * F_IN + kb + cl * 4, tile + slotbase * 4);
        }
        __syncthreads();

        #pragma unroll
        for (int ks = 0; ks < 4; ks++) {
            int kc = (kb >> 5) + ks;
            short8 ah[2], al[2];
            #pragma unroll
            for (int m = 0; m < 2; m++) {
                int r  = m * 64 + w * 16 + lr;
                int c0 = ks * 8 + lg * 2;
                f32x4 v0 = *(const f32x4*)&tile[r * BK + ((c0 ^ (r & 7)) << 2)];
                f32x4 v1 = *(const f32x4*)&tile[r * BK + (((c0 + 1) ^ (r & 7)) << 2)];
                split8(v0, v1, ah[m], al[m]);
            }
            #pragma unroll
            for (int nt = 0; nt < 4; nt++) {
                long bo = ((((long)nt * 16 + kc) * 2) * 64 + l) * 8;
                short8 bh8 = *(const short8*)(Wg + bo);
                short8 bl8 = *(const short8*)(Wg + bo + 512);
                #pragma unroll
                for (int m = 0; m < 2; m++) {
                    acc[m][nt] = __builtin_amdgcn_mfma_f32_16x16x32_bf16(ah[m], bh8, acc[m][nt], 0, 0, 0);
                    acc[m][nt] = __builtin_amdgcn_mfma_f32_16x16x32_bf16(ah[m], bl8, acc[m][nt], 0, 0, 0);
                    acc[m][nt] = __builtin_amdgcn_mfma_f32_16x16x32_bf16(al[m], bh8, acc[m][nt], 0, 0, 0);
                }
            }
        }
        __syncthreads();
    }

    // epilogue: C/D layout col = lane&15, row = (lane>>4)*4 + reg
    #pragma unroll
    for (int m = 0; m < 2; m++) {
        #pragma unroll
        for (int nt = 0; nt < 4; nt++) {
            #pragma unroll
            for (int r = 0; r < 4; r++) {
                int row = row0 + m * 64 + w * 16 + lg * 4 + r;
                if (row < N_NODES)
                    support[(long)row * HID + nt * 16 + lr] = acc[m][nt][r];
            }
        }
    }
}

// ---------------------------------------------------------------------------
// CSR build 5: within-bucket final scatter; node degrees + LDS scan ->
// off[] and cursors locally; zero global atomics.
// ---------------------------------------------------------------------------
__global__ __launch_bounds__(512) void partB2(const int* __restrict__ bbase,
                                              const int* __restrict__ bsums,
                                              const int2* __restrict__ mid,
                                              int2* __restrict__ epk,
                                              int* __restrict__ off) {
    __shared__ int nh[1024];
    __shared__ int sc[512];
    int t = threadIdx.x;
    int b = blockIdx.x;
    int start = bbase[b];
    int cntb  = bsums[b];

    nh[t] = 0; nh[t + 512] = 0;
    __syncthreads();

    for (int i = t; i < cntb; i += 512) {
        u32 ux = (u32)mid[start + i].x;
        atomicAdd(&nh[ux >> 17], 1);
    }
    __syncthreads();

    int c0 = nh[2 * t], c1 = nh[2 * t + 1];
    int s = c0 + c1;
    sc[t] = s;
    __syncthreads();
    #pragma unroll
    for (int d = 1; d < 512; d <<= 1) {
        int u = (t >= d) ? sc[t - d] : 0;
        __syncthreads();
        sc[t] += u;
        __syncthreads();
    }
    int ex = start + sc[t] - s;

    nh[2 * t]     = ex;
    nh[2 * t + 1] = ex + c0;
    int node = (b << 10) + 2 * t;
    if (node < N_NODES)     off[node]     = ex;
    if (node + 1 < N_NODES) off[node + 1] = ex + c0;
    __syncthreads();

    for (int i = t; i < cntb; i += 512) {
        int2 m = mid[start + i];
        u32 ux = (u32)m.x;
        int pos = atomicAdd(&nh[ux >> 17], 1);
        epk[pos] = make_int2((int)(ux & 0x1FFFF), m.y);
    }
}

// ---------------------------------------------------------------------------
// SPMM1 + bias + relu + GEMM2 fused (R10-PROVEN): grid-stride, one wave per
// node, float1 full-row gathers, 8/4/1 cascade. W2 staged once per block.
// ---------------------------------------------------------------------------
__global__ __launch_bounds__(256) void spmm1_fused(const int* __restrict__ off,
                                                   const int2* __restrict__ epk,
                                                   const float* __restrict__ sup,
                                                   const float* __restrict__ b1,
                                                   const float* __restrict__ W2,
                                                   float* __restrict__ sup2) {
    __shared__ float w2s[HID * NCLS];   // [k][c]
    __shared__ float hrow[2][4][HID];
    int tid = threadIdx.x;
    for (int i = tid; i < HID * NCLS; i += 256) w2s[i] = W2[i];
    __syncthreads();

    int lane = tid & 63;
    int w    = tid >> 6;
    int c    = lane & 15, q = lane >> 4;
    float bl = b1[lane];

    for (int g = blockIdx.x; g < N_NODES / 4; g += gridDim.x) {
        int n = g * 4 + w;              // N_NODES % 4 == 0
        int e0 = off[n];
        int e1 = off[n + 1];
        float acc = 0.f;
        int e = e0;
        for (; e + 7 < e1; e += 8) {
            int2 p[8];
            float gg[8];
            #pragma unroll
            for (int j = 0; j < 8; j++) p[j] = epk[e + j];
            #pragma unroll
            for (int j = 0; j < 8; j++) gg[j] = sup[(long)p[j].x * HID + lane];
            #pragma unroll
            for (int j = 0; j < 8; j++) acc += __int_as_float(p[j].y) * gg[j];
        }
        for (; e + 3 < e1; e += 4) {
            int2 p0 = epk[e],     p1 = epk[e + 1];
            int2 p2 = epk[e + 2], p3 = epk[e + 3];
            float g0 = sup[(long)p0.x * HID + lane];
            float g1 = sup[(long)p1.x * HID + lane];
            float g2 = sup[(long)p2.x * HID + lane];
            float g3 = sup[(long)p3.x * HID + lane];
            acc += __int_as_float(p0.y) * g0 + __int_as_float(p1.y) * g1
                 + __int_as_float(p2.y) * g2 + __int_as_float(p3.y) * g3;
        }
        for (; e < e1; e++) {
            int2 p = epk[e];
            acc += __int_as_float(p.y) * sup[(long)p.x * HID + lane];
        }
        float hv = fmaxf(acc + bl, 0.f);

        int par = g & 1;
        hrow[par][w][lane] = hv;
        asm volatile("s_waitcnt lgkmcnt(0)" ::: "memory");   // wave-local drain
        __builtin_amdgcn_sched_barrier(0);                   // rule #18 fence

        float part = 0.f;
        #pragma unroll
        for (int k0 = 0; k0 < 16; k0++) {
            int k = q * 16 + k0;
            part += hrow[par][w][k] * w2s[k * NCLS + c];
        }
        part += __shfl_xor(part, 16);
        part += __shfl_xor(part, 32);
        if (lane < 16) sup2[(long)n * NCLS + c] = part;
    }
}

// ---------------------------------------------------------------------------
// SPMM2 (CSR) fused with +b2 and softmax (R10-PROVEN one-shot form).
// 16 lanes per node, 8/4/1 cascade gathers.
// ---------------------------------------------------------------------------
__global__ __launch_bounds__(256) void spmm2_softmax(const int* __restrict__ off,
                                                     const int2* __restrict__ epk,
                                                     const float* __restrict__ sup2,
                                                     const float* __restrict__ b2,
                                                     float* __restrict__ out) {
    int tid = threadIdx.x;
    int n   = blockIdx.x * 16 + (tid >> 4);
    int c   = tid & 15;
    if (n >= N_NODES) return;

    int e0 = off[n];
    int e1 = off[n + 1];
    float acc = 0.f;
    int e = e0;
    for (; e + 7 < e1; e += 8) {
        int2 p[8];
        float g[8];
        #pragma unroll
        for (int j = 0; j < 8; j++) p[j] = epk[e + j];
        #pragma unroll
        for (int j = 0; j < 8; j++) g[j] = sup2[(long)p[j].x * NCLS + c];
        #pragma unroll
        for (int j = 0; j < 8; j++) acc += __int_as_float(p[j].y) * g[j];
    }
    for (; e + 3 < e1; e += 4) {
        int2 p0 = epk[e],     p1 = epk[e + 1];
        int2 p2 = epk[e + 2], p3 = epk[e + 3];
        float g0 = sup2[(long)p0.x * NCLS + c];
        float g1 = sup2[(long)p1.x * NCLS + c];
        float g2 = sup2[(long)p2.x * NCLS + c];
        float g3 = sup2[(long)p3.x * NCLS + c];
        acc += __int_as_float(p0.y) * g0 + __int_as_float(p1.y) * g1
             + __int_as_float(p2.y) * g2 + __int_as_float(p3.y) * g3;
    }
    for (; e < e1; e++) {
        int2 p = epk[e];
        acc += __int_as_float(p.y) * sup2[(long)p.x * NCLS + c];
    }

    float lg = acc + b2[c];
    float m = lg;
    #pragma unroll
    for (int mask = 1; mask < 16; mask <<= 1)
        m = fmaxf(m, __shfl_xor(m, mask, 16));
    float p = expf(lg - m);
    float s = p;
    #pragma unroll
    for (int mask = 1; mask < 16; mask <<= 1)
        s += __shfl_xor(s, mask, 16);
    out[(long)n * NCLS + c] = p / s;
}

// ---------------------------------------------------------------------------
extern "C" void kernel_launch(void* const* d_in, const int* in_sizes, int n_in,
                              void* d_out, int out_size, void* d_ws, size_t ws_size,
                              hipStream_t stream) {
    const float* x     = (const float*)d_in[0];
    const int*   esrc  = (const int*)  d_in[1];
    const int*   edst  = (const int*)  d_in[2];
    const float* eval_ = (const float*)d_in[3];
    const float* W1    = (const float*)d_in[4];
    const float* b1    = (const float*)d_in[5];
    const float* W2    = (const float*)d_in[6];
    const float* b2    = (const float*)d_in[7];
    float* out = (float*)d_out;

    // workspace layout (4B units; every base 16B-aligned)
    float* sup1  = (float*)d_ws;                        // 6,400,000 f
    float* sup2  = sup1 + (long)N_NODES * HID;          // 1,600,000 f
    int2*  epk   = (int2*)(sup2 + (long)N_NODES * NCLS);// 1,600,000 int2
    int*   off   = (int*)(epk + N_EDGES);               // 100,004 i
    int*   bsums = off + 100004;                        // 128 i
    int*   bbase = bsums + 128;                         // 128 i
    int*   bh    = bbase + 128;                         // 38,320 i (98x391)
    unsigned short* Wg = (unsigned short*)(bh + 38320); // 65,536 us (128 KB)
    int2*  mid   = (int2*)(Wg + 65536);                 // 1,600,000 int2

    // --- CSR build (scan-based, no global atomics) + fused W1 prep ---
    bhist_prep<<<PA_NB + PREP_NB, 256, 0, stream>>>(edst, bh, W1, Wg);
    colscan<<<SCAN_NB, 512, 0, stream>>>(bh, bsums);
    scan_top<<<1,      128, 0, stream>>>(bsums, bbase, off);

    // --- fused partA2 (edge partition) + gemm1 (x @ W1): independent work
    //     overlapped in one dispatch; partA blocks first in dispatch order ---
    partA_gemm1<<<PA_NB + GEMM_NB, 256, 0, stream>>>(esrc, edst, eval_, bh,
                                                     bbase, mid, x, Wg, sup1);

    partB2<<<SCAN_NB, 512, 0, stream>>>(bbase, bsums, mid, epk, off);

    // --- layer 1 aggregate + MLP, layer 2 + softmax ---
    spmm1_fused<<<4096, 256, 0, stream>>>(off, epk, sup1, b1, W2, sup2);
    spmm2_softmax<<<(N_NODES + 15) / 16, 256, 0, stream>>>(off, epk, sup2, b2, out);
}

// Round 16
// 197.178 us; speedup vs baseline: 1.1630x; 1.0388x over previous
//
#include <hip/hip_runtime.h>
#include <hip/hip_bf16.h>

#define N_NODES 100000
#define N_EDGES 1600000
#define F_IN    512
#define HID     64
#define NCLS    16

#define BSH     9       // bucket shift: 512-node buckets
#define SCAN_NB 196     // ceil(100000 / 512)
#define BM      128     // gemm1 row tile
#define BK      128     // gemm1 k tile
#define PA_EPB  4096    // partition edges per block
#define PA_NB   ((N_EDGES + PA_EPB - 1) / PA_EPB)   // 391
#define PREP_NB 128     // prep_w1 blocks fused behind bhist
#define GEMM_NB ((N_NODES + BM - 1) / BM)           // 782

typedef __attribute__((ext_vector_type(8))) short short8;
typedef __attribute__((ext_vector_type(4))) float f32x4;
typedef unsigned int u32;
typedef unsigned short u16;

// ---------------------------------------------------------------------------
// async global->LDS 16B (wave-uniform LDS base + lane*16 dest semantics)
// ---------------------------------------------------------------------------
__device__ inline void gload_lds16(const float* g, float* l) {
    __builtin_amdgcn_global_load_lds(
        (const __attribute__((address_space(1))) u32*)g,
        (__attribute__((address_space(3))) u32*)l, 16, 0, 0);
}

// ---------------------------------------------------------------------------
// split fp32 -> bf16 hi + bf16 lo (truncation; residual ~2^-16 relative)
// ---------------------------------------------------------------------------
__device__ inline void split_bf16(float a, unsigned short& hi, unsigned short& lo) {
    unsigned u = __float_as_uint(a);
    hi = (unsigned short)(u >> 16);
    float hif = __uint_as_float(((unsigned)hi) << 16);
    float lof = a - hif;
    lo = (unsigned short)(__float_as_uint(lof) >> 16);
}

// split 8 fp32 (two f32x4) into hi/lo short8 fragments
__device__ inline void split8(f32x4 a, f32x4 b, short8& hi, short8& lo) {
    #pragma unroll
    for (int i = 0; i < 4; i++) {
        u16 h, l;
        split_bf16(a[i], h, l);
        hi[i] = (short)h; lo[i] = (short)l;
    }
    #pragma unroll
    for (int i = 0; i < 4; i++) {
        u16 h, l;
        split_bf16(b[i], h, l);
        hi[4 + i] = (short)h; lo[4 + i] = (short)l;
    }
}

// ---------------------------------------------------------------------------
// FUSED CSR build 1 + W1 prep (disjoint block ranges, disjoint in/out):
//  blocks [0, PA_NB):          per-block bucket histogram -> bh[bucket][blk]
//  blocks [PA_NB, PA_NB+128):  W1 [512][64] fp32 -> Wg fragment-native
//                              bf16 hi/lo
// ---------------------------------------------------------------------------
__global__ __launch_bounds__(256) void bhist_prep(const int* __restrict__ edst,
                                                  int* __restrict__ bh,
                                                  const float* __restrict__ W1,
                                                  unsigned short* __restrict__ Wg) {
    int tid = threadIdx.x;
    if (blockIdx.x >= PA_NB) {
        // --- prep_w1 role ---
        int idx = (blockIdx.x - PA_NB) * 256 + tid;   // 0 .. 32767
        if (idx < F_IN * HID) {
            int k = idx >> 6, n = idx & 63;
            unsigned short hi, lo;
            split_bf16(W1[idx], hi, lo);
            int nt = n >> 4, kc = k >> 5;
            int l  = ((k >> 3) & 3) * 16 + (n & 15);
            int j  = k & 7;
            long base = ((((long)nt * 16 + kc) * 2) * 64 + l) * 8 + j;
            Wg[base]       = hi;
            Wg[base + 512] = lo;
        }
        return;
    }
    // --- bhist role ---
    __shared__ int hist[SCAN_NB];
    int e00 = blockIdx.x * PA_EPB;
    for (int i = tid; i < SCAN_NB; i += 256) hist[i] = 0;
    __syncthreads();
    #pragma unroll
    for (int j = 0; j < PA_EPB / 256; j++) {
        int e = e00 + j * 256 + tid;
        if (e < N_EDGES) atomicAdd(&hist[edst[e] >> BSH], 1);
    }
    __syncthreads();
    for (int i = tid; i < SCAN_NB; i += 256)
        bh[i * PA_NB + blockIdx.x] = hist[i];
}

// ---------------------------------------------------------------------------
// CSR build 2: per bucket, exclusive scan over the 391 block counts
// ---------------------------------------------------------------------------
__global__ __launch_bounds__(512) void colscan(int* __restrict__ bh,
                                               int* __restrict__ bsums) {
    __shared__ int sc[512];
    int t = threadIdx.x;
    int b = blockIdx.x;
    int v = (t < PA_NB) ? bh[b * PA_NB + t] : 0;
    sc[t] = v;
    __syncthreads();
    #pragma unroll
    for (int d = 1; d < 512; d <<= 1) {
        int u = (t >= d) ? sc[t - d] : 0;
        __syncthreads();
        sc[t] += u;
        __syncthreads();
    }
    if (t < PA_NB) bh[b * PA_NB + t] = sc[t] - v;   // exclusive
    if (t == 511) bsums[b] = sc[511];
}

// ---------------------------------------------------------------------------
// CSR build 3: exclusive scan of 196 bucket sums -> bbase; off[N]=E.
// ---------------------------------------------------------------------------
__global__ __launch_bounds__(256) void scan_top(const int* __restrict__ bsums,
                                                int* __restrict__ bbase,
                                                int* __restrict__ off) {
    __shared__ int sc[256];
    int t = threadIdx.x;
    int v0 = (t < SCAN_NB) ? bsums[t] : 0;
    sc[t] = v0;
    __syncthreads();
    #pragma unroll
    for (int d = 1; d < 256; d <<= 1) {
        int v = (t >= d) ? sc[t - d] : 0;
        __syncthreads();
        sc[t] += v;
        __syncthreads();
    }
    bbase[t] = sc[t] - v0;
    if (t == 0) off[N_NODES] = N_EDGES;
}

// ---------------------------------------------------------------------------
// FUSED partA2 + GEMM1 (disjoint block ranges, disjoint inputs/outputs):
//  blocks [0, PA_NB):  partA2 — bucket edges by dst>>9 into mid[] via
//      deterministic reservations; LDS cursors; drains under gemm1.
//  blocks [PA_NB, PA_NB+GEMM_NB):  gemm1 (R8/R10-proven).
//  mid.x packs src (17b) | dst_low9 << 17.
// ---------------------------------------------------------------------------
__global__ __launch_bounds__(256, 2) void partA_gemm1(
        const int* __restrict__ esrc, const int* __restrict__ edst,
        const float* __restrict__ eval_, const int* __restrict__ bh,
        const int* __restrict__ bbase, int2* __restrict__ mid,
        const float* __restrict__ x, const unsigned short* __restrict__ Wg,
        float* __restrict__ support) {
    __shared__ float tile[BM * BK];   // 64 KB (gemm role)
    __shared__ int   curs[SCAN_NB];   // partA role

    const int tid = threadIdx.x;

    if (blockIdx.x < PA_NB) {
        // ---------------- partA2 role ----------------
        int blk = blockIdx.x;
        int e00 = blk * PA_EPB;
        for (int i = tid; i < SCAN_NB; i += 256)
            curs[i] = bbase[i] + bh[i * PA_NB + blk];
        __syncthreads();
        #pragma unroll
        for (int j = 0; j < PA_EPB / 256; j++) {
            int e = e00 + j * 256 + tid;
            if (e < N_EDGES) {
                int d = edst[e];
                int b = d >> BSH;
                int pos = atomicAdd(&curs[b], 1);
                mid[pos] = make_int2(esrc[e] | ((d & 511) << 17),
                                     __float_as_int(eval_[e]));
            }
        }
        return;
    }

    // ---------------- gemm1 role ----------------
    const int l    = tid & 63;
    const int w    = tid >> 6;
    const int lr   = l & 15;
    const int lg   = l >> 4;
    const int row0 = (blockIdx.x - PA_NB) * BM;

    f32x4 acc[2][4] = {};

    for (int kb = 0; kb < F_IN; kb += BK) {
        // --- stage: 128 rows x 32 chunks = 4096 16B slots ---
        #pragma unroll
        for (int j = 0; j < 16; j++) {
            int slotbase = j * 256 + w * 64;        // wave-uniform
            int slot     = slotbase + l;
            int row      = slot >> 5;               // 32 chunks per row
            int cl       = (slot & 31) ^ (row & 7); // inverse swizzle on src
            int rr       = row0 + row;
            if (rr > N_NODES - 1) rr = N_NODES - 1; // clamp (rows >= N discarded)
            gload_lds16(x + (long)rr * F_IN + kb + cl * 4, tile + slotbase * 4);
        }
        __syncthreads();

        #pragma unroll
        for (int ks = 0; ks < 4; ks++) {
            int kc = (kb >> 5) + ks;
            short8 ah[2], al[2];
            #pragma unroll
            for (int m = 0; m < 2; m++) {
                int r  = m * 64 + w * 16 + lr;
                int c0 = ks * 8 + lg * 2;
                f32x4 v0 = *(const f32x4*)&tile[r * BK + ((c0 ^ (r & 7)) << 2)];
                f32x4 v1 = *(const f32x4*)&tile[r * BK + (((c0 + 1) ^ (r & 7)) << 2)];
                split8(v0, v1, ah[m], al[m]);
            }
            #pragma unroll
            for (int nt = 0; nt < 4; nt++) {
                long bo = ((((long)nt * 16 + kc) * 2) * 64 + l) * 8;
                short8 bh8 = *(const short8*)(Wg + bo);
                short8 bl8 = *(const short8*)(Wg + bo + 512);
                #pragma unroll
                for (int m = 0; m < 2; m++) {
                    acc[m][nt] = __builtin_amdgcn_mfma_f32_16x16x32_bf16(ah[m], bh8, acc[m][nt], 0, 0, 0);
                    acc[m][nt] = __builtin_amdgcn_mfma_f32_16x16x32_bf16(ah[m], bl8, acc[m][nt], 0, 0, 0);
                    acc[m][nt] = __builtin_amdgcn_mfma_f32_16x16x32_bf16(al[m], bh8, acc[m][nt], 0, 0, 0);
                }
            }
        }
        __syncthreads();
    }

    // epilogue: C/D layout col = lane&15, row = (lane>>4)*4 + reg
    #pragma unroll
    for (int m = 0; m < 2; m++) {
        #pragma unroll
        for (int nt = 0; nt < 4; nt++) {
            #pragma unroll
            for (int r = 0; r < 4; r++) {
                int row = row0 + m * 64 + w * 16 + lg * 4 + r;
                if (row < N_NODES)
                    support[(long)row * HID + nt * 16 + lr] = acc[m][nt][r];
            }
        }
    }
}

// ---------------------------------------------------------------------------
// CSR build 5: within-bucket final scatter. 512-node buckets -> 196 blocks
// (~2x CU fill vs 98), one node-cursor per thread, zero global atomics.
// ---------------------------------------------------------------------------
__global__ __launch_bounds__(512) void partB2(const int* __restrict__ bbase,
                                              const int* __restrict__ bsums,
                                              const int2* __restrict__ mid,
                                              int2* __restrict__ epk,
                                              int* __restrict__ off) {
    __shared__ int nh[512];
    __shared__ int sc[512];
    int t = threadIdx.x;
    int b = blockIdx.x;
    int start = bbase[b];
    int cntb  = bsums[b];

    nh[t] = 0;
    __syncthreads();

    // pass 1: node-degree histogram within bucket
    for (int i = t; i < cntb; i += 512) {
        u32 ux = (u32)mid[start + i].x;
        atomicAdd(&nh[ux >> 17], 1);
    }
    __syncthreads();

    // 512-wide scan (one node per thread)
    int c0 = nh[t];
    sc[t] = c0;
    __syncthreads();
    #pragma unroll
    for (int d = 1; d < 512; d <<= 1) {
        int u = (t >= d) ? sc[t - d] : 0;
        __syncthreads();
        sc[t] += u;
        __syncthreads();
    }
    int ex = start + sc[t] - c0;       // exclusive prefix for this node

    nh[t] = ex;                         // global cursor
    int node = (b << BSH) + t;
    if (node < N_NODES) off[node] = ex;
    __syncthreads();

    // pass 2: scatter to final dst-sorted order
    for (int i = t; i < cntb; i += 512) {
        int2 m = mid[start + i];
        u32 ux = (u32)m.x;
        int pos = atomicAdd(&nh[ux >> 17], 1);
        epk[pos] = make_int2((int)(ux & 0x1FFFF), m.y);
    }
}

// ---------------------------------------------------------------------------
// SPMM1 + bias + relu + GEMM2 fused (R10-PROVEN): grid-stride, one wave per
// node, float1 full-row gathers, 8/4/1 cascade. W2 staged once per block.
// ---------------------------------------------------------------------------
__global__ __launch_bounds__(256) void spmm1_fused(const int* __restrict__ off,
                                                   const int2* __restrict__ epk,
                                                   const float* __restrict__ sup,
                                                   const float* __restrict__ b1,
                                                   const float* __restrict__ W2,
                                                   float* __restrict__ sup2) {
    __shared__ float w2s[HID * NCLS];   // [k][c]
    __shared__ float hrow[2][4][HID];
    int tid = threadIdx.x;
    for (int i = tid; i < HID * NCLS; i += 256) w2s[i] = W2[i];
    __syncthreads();

    int lane = tid & 63;
    int w    = tid >> 6;
    int c    = lane & 15, q = lane >> 4;
    float bl = b1[lane];

    for (int g = blockIdx.x; g < N_NODES / 4; g += gridDim.x) {
        int n = g * 4 + w;              // N_NODES % 4 == 0
        int e0 = off[n];
        int e1 = off[n + 1];
        float acc = 0.f;
        int e = e0;
        for (; e + 7 < e1; e += 8) {
            int2 p[8];
            float gg[8];
            #pragma unroll
            for (int j = 0; j < 8; j++) p[j] = epk[e + j];
            #pragma unroll
            for (int j = 0; j < 8; j++) gg[j] = sup[(long)p[j].x * HID + lane];
            #pragma unroll
            for (int j = 0; j < 8; j++) acc += __int_as_float(p[j].y) * gg[j];
        }
        for (; e + 3 < e1; e += 4) {
            int2 p0 = epk[e],     p1 = epk[e + 1];
            int2 p2 = epk[e + 2], p3 = epk[e + 3];
            float g0 = sup[(long)p0.x * HID + lane];
            float g1 = sup[(long)p1.x * HID + lane];
            float g2 = sup[(long)p2.x * HID + lane];
            float g3 = sup[(long)p3.x * HID + lane];
            acc += __int_as_float(p0.y) * g0 + __int_as_float(p1.y) * g1
                 + __int_as_float(p2.y) * g2 + __int_as_float(p3.y) * g3;
        }
        for (; e < e1; e++) {
            int2 p = epk[e];
            acc += __int_as_float(p.y) * sup[(long)p.x * HID + lane];
        }
        float hv = fmaxf(acc + bl, 0.f);

        int par = g & 1;
        hrow[par][w][lane] = hv;
        asm volatile("s_waitcnt lgkmcnt(0)" ::: "memory");   // wave-local drain
        __builtin_amdgcn_sched_barrier(0);                   // rule #18 fence

        float part = 0.f;
        #pragma unroll
        for (int k0 = 0; k0 < 16; k0++) {
            int k = q * 16 + k0;
            part += hrow[par][w][k] * w2s[k * NCLS + c];
        }
        part += __shfl_xor(part, 16);
        part += __shfl_xor(part, 32);
        if (lane < 16) sup2[(long)n * NCLS + c] = part;
    }
}

// ---------------------------------------------------------------------------
// SPMM2 (CSR) fused with +b2 and softmax (R10-PROVEN one-shot form).
// 16 lanes per node, 8/4/1 cascade gathers.
// ---------------------------------------------------------------------------
__global__ __launch_bounds__(256) void spmm2_softmax(const int* __restrict__ off,
                                                     const int2* __restrict__ epk,
                                                     const float* __restrict__ sup2,
                                                     const float* __restrict__ b2,
                                                     float* __restrict__ out) {
    int tid = threadIdx.x;
    int n   = blockIdx.x * 16 + (tid >> 4);
    int c   = tid & 15;
    if (n >= N_NODES) return;

    int e0 = off[n];
    int e1 = off[n + 1];
    float acc = 0.f;
    int e = e0;
    for (; e + 7 < e1; e += 8) {
        int2 p[8];
        float g[8];
        #pragma unroll
        for (int j = 0; j < 8; j++) p[j] = epk[e + j];
        #pragma unroll
        for (int j = 0; j < 8; j++) g[j] = sup2[(long)p[j].x * NCLS + c];
        #pragma unroll
        for (int j = 0; j < 8; j++) acc += __int_as_float(p[j].y) * g[j];
    }
    for (; e + 3 < e1; e += 4) {
        int2 p0 = epk[e],     p1 = epk[e + 1];
        int2 p2 = epk[e + 2], p3 = epk[e + 3];
        float g0 = sup2[(long)p0.x * NCLS + c];
        float g1 = sup2[(long)p1.x * NCLS + c];
        float g2 = sup2[(long)p2.x * NCLS + c];
        float g3 = sup2[(long)p3.x * NCLS + c];
        acc += __int_as_float(p0.y) * g0 + __int_as_float(p1.y) * g1
             + __int_as_float(p2.y) * g2 + __int_as_float(p3.y) * g3;
    }
    for (; e < e1; e++) {
        int2 p = epk[e];
        acc += __int_as_float(p.y) * sup2[(long)p.x * NCLS + c];
    }

    float lg = acc + b2[c];
    float m = lg;
    #pragma unroll
    for (int mask = 1; mask < 16; mask <<= 1)
        m = fmaxf(m, __shfl_xor(m, mask, 16));
    float p = expf(lg - m);
    float s = p;
    #pragma unroll
    for (int mask = 1; mask < 16; mask <<= 1)
        s += __shfl_xor(s, mask, 16);
    out[(long)n * NCLS + c] = p / s;
}

// ---------------------------------------------------------------------------
extern "C" void kernel_launch(void* const* d_in, const int* in_sizes, int n_in,
                              void* d_out, int out_size, void* d_ws, size_t ws_size,
                              hipStream_t stream) {
    const float* x     = (const float*)d_in[0];
    const int*   esrc  = (const int*)  d_in[1];
    const int*   edst  = (const int*)  d_in[2];
    const float* eval_ = (const float*)d_in[3];
    const float* W1    = (const float*)d_in[4];
    const float* b1    = (const float*)d_in[5];
    const float* W2    = (const float*)d_in[6];
    const float* b2    = (const float*)d_in[7];
    float* out = (float*)d_out;

    // workspace layout (4B units; every base 16B-aligned)
    float* sup1  = (float*)d_ws;                        // 6,400,000 f
    float* sup2  = sup1 + (long)N_NODES * HID;          // 1,600,000 f
    int2*  epk   = (int2*)(sup2 + (long)N_NODES * NCLS);// 1,600,000 int2
    int*   off   = (int*)(epk + N_EDGES);               // 100,004 i
    int*   bsums = off + 100004;                        // 256 i
    int*   bbase = bsums + 256;                         // 256 i
    int*   bh    = bbase + 256;                         // 76,636 i (196x391)
    unsigned short* Wg = (unsigned short*)(bh + 76640); // 65,536 us (128 KB)
    int2*  mid   = (int2*)(Wg + 65536);                 // 1,600,000 int2

    // --- CSR build (scan-based, no global atomics) + fused W1 prep ---
    bhist_prep<<<PA_NB + PREP_NB, 256, 0, stream>>>(edst, bh, W1, Wg);
    colscan<<<SCAN_NB, 512, 0, stream>>>(bh, bsums);
    scan_top<<<1,      256, 0, stream>>>(bsums, bbase, off);

    // --- fused partA2 (edge partition) + gemm1 (x @ W1) ---
    partA_gemm1<<<PA_NB + GEMM_NB, 256, 0, stream>>>(esrc, edst, eval_, bh,
                                                     bbase, mid, x, Wg, sup1);

    partB2<<<SCAN_NB, 512, 0, stream>>>(bbase, bsums, mid, epk, off);

    // --- layer 1 aggregate + MLP, layer 2 + softmax ---
    spmm1_fused<<<4096, 256, 0, stream>>>(off, epk, sup1, b1, W2, sup2);
    spmm2_softmax<<<(N_NODES + 15) / 16, 256, 0, stream>>>(off, epk, sup2, b2, out);
}